// Round 9
// baseline (257.752 us; speedup 1.0000x reference)
//
#include <hip/hip_runtime.h>

#define NEG_SLOPE 0.01f
#define EPB 4096          // edges per block in bucket build
#define NB_SHIFT 8        // 256 dst-nodes per bucket

typedef __attribute__((ext_vector_type(8))) short bf16x8;
typedef __attribute__((ext_vector_type(4))) float floatx4;

__device__ __forceinline__ short f2bf(float f) {
    union { float f; unsigned u; } v; v.f = f;
    unsigned u = v.u;
    u += 0x7FFF + ((u >> 16) & 1);          // round-to-nearest-even
    return (short)(u >> 16);
}
__device__ __forceinline__ float bf2f(short s) {
    union { unsigned u; float f; } v;
    v.u = ((unsigned)(unsigned short)s) << 16;
    return v.f;
}

// ---------------- bucketed CSR build (degrees derived in-bucket; no global scan) ----------------
// Bucket k holds dst in [k*256, (k+1)*256). hist layout bucket-major: hist[k*B + b].

__global__ void bucket_hist(const int* __restrict__ dst, int E, int B, int K,
                            int* __restrict__ hist) {
    __shared__ int lh[1024];
    int b = blockIdx.x;
    for (int i = threadIdx.x; i < K; i += 256) lh[i] = 0;
    __syncthreads();
    int lo = b * EPB, hi = min(lo + EPB, E);
    for (int e = lo + threadIdx.x; e < hi; e += 256)
        atomicAdd(&lh[dst[e] >> NB_SHIFT], 1);
    __syncthreads();
    for (int i = threadIdx.x; i < K; i += 256)
        hist[i * B + b] = lh[i];
}

// one block: bucket totals + exclusive scan -> bstart[0..K], bstart[K]=E
__global__ void bucket_starts(const int* __restrict__ hist, int B, int K, int E,
                              int* __restrict__ bstart) {
    __shared__ int tot[1024];
    __shared__ int waveTot[4];
    __shared__ int waveOff[5];
    int tid = threadIdx.x;                 // 256 threads
    for (int k = tid; k < K; k += 256) {
        const int* hp = hist + (size_t)k * B;
        int s = 0;
        for (int b = 0; b < B; b++) s += hp[b];
        tot[k] = s;
    }
    __syncthreads();
    int lane = tid & 63, wave = tid >> 6;
    int run = 0;
    for (int lo = 0; lo < K; lo += 256) {
        int i = lo + tid;
        int v = (i < K) ? tot[i] : 0;
        int s = v;
        #pragma unroll
        for (int o = 1; o < 64; o <<= 1) {
            int t = __shfl_up(s, o);
            if (lane >= o) s += t;
        }
        if (lane == 63) waveTot[wave] = s;
        __syncthreads();
        if (tid == 0) {
            int acc = 0;
            #pragma unroll
            for (int w = 0; w < 4; w++) { waveOff[w] = acc; acc += waveTot[w]; }
            waveOff[4] = acc;
        }
        __syncthreads();
        if (i < K) bstart[i] = run + s - v + waveOff[wave];
        run += waveOff[4];
        __syncthreads();
    }
    if (tid == 0) bstart[K] = E;
}

// per-bucket exclusive scan of hist[k*B .. k*B+B), seeded with bstart[k].
__global__ void scan_hist_buckets(int* __restrict__ hist, const int* __restrict__ bstart,
                                  int B, int K) {
    __shared__ int waveTot[4];
    __shared__ int waveOff[5];
    int k = blockIdx.x;
    int tid = threadIdx.x;
    int lane = tid & 63, wave = tid >> 6;
    int* hp = hist + (size_t)k * B;
    int run = bstart[k];
    for (int lo = 0; lo < B; lo += 256) {
        int i = lo + tid;
        int v = (i < B) ? hp[i] : 0;
        int s = v;
        #pragma unroll
        for (int o = 1; o < 64; o <<= 1) {
            int t = __shfl_up(s, o);
            if (lane >= o) s += t;
        }
        if (lane == 63) waveTot[wave] = s;
        __syncthreads();
        if (tid == 0) {
            int acc = 0;
            #pragma unroll
            for (int w = 0; w < 4; w++) { waveOff[w] = acc; acc += waveTot[w]; }
            waveOff[4] = acc;
        }
        __syncthreads();
        if (i < B) hp[i] = run + s - v + waveOff[wave];
        run += waveOff[4];
        __syncthreads();
    }
}

// scatter edges into bucket-contiguous order; 4B records: src | local_dst<<24 (needs N < 2^24)
__global__ void bucket_scatter(const int* __restrict__ src, const int* __restrict__ dst,
                               int E, int B, int K, const int* __restrict__ scanned,
                               unsigned* __restrict__ bucketed) {
    __shared__ int lcur[1024];
    int b = blockIdx.x;
    for (int i = threadIdx.x; i < K; i += 256) lcur[i] = scanned[i * B + b];
    __syncthreads();
    int lo = b * EPB, hi = min(lo + EPB, E);
    for (int e = lo + threadIdx.x; e < hi; e += 256) {
        int d = dst[e];
        unsigned rec = (unsigned)src[e] | ((unsigned)(d & 255) << 24);
        int pos = atomicAdd(&lcur[d >> NB_SHIFT], 1);
        bucketed[pos] = rec;
    }
}

// one block per bucket: derive degrees, row_ptr/row_end/dis, then fill csr_src.
__global__ void fill_csr_deg(const unsigned* __restrict__ bucketed,
                             const int* __restrict__ bstart,
                             int* __restrict__ row_ptr, int* __restrict__ row_end,
                             float* __restrict__ dis,
                             int* __restrict__ csr_src, int N) {
    __shared__ int cnt[256];
    __shared__ int rp[256];
    __shared__ int waveTot[4];
    __shared__ int waveOff[4];
    int k = blockIdx.x;
    int tid = threadIdx.x;
    int base = k << NB_SHIFT;
    cnt[tid] = 0;
    __syncthreads();
    int lo = bstart[k], hi = bstart[k + 1];
    for (int e = lo + tid; e < hi; e += 256)
        atomicAdd(&cnt[bucketed[e] >> 24], 1);
    __syncthreads();
    int v = cnt[tid];
    int lane = tid & 63, wave = tid >> 6;
    int s = v;
    #pragma unroll
    for (int o = 1; o < 64; o <<= 1) {
        int t = __shfl_up(s, o);
        if (lane >= o) s += t;
    }
    if (lane == 63) waveTot[wave] = s;
    __syncthreads();
    if (tid == 0) {
        int acc = 0;
        #pragma unroll
        for (int w = 0; w < 4; w++) { waveOff[w] = acc; acc += waveTot[w]; }
    }
    __syncthreads();
    int myrp = lo + s - v + waveOff[wave];
    rp[tid] = myrp;
    int node = base + tid;
    if (node < N) {
        row_ptr[node] = myrp;
        row_end[node] = myrp + v;
        dis[node] = rsqrtf(1.0f + (float)v);   // self-loop folded into degree
    }
    __syncthreads();
    for (int e = lo + tid; e < hi; e += 256) {
        unsigned sd = bucketed[e];
        int pos = atomicAdd(&rp[sd >> 24], 1);
        csr_src[pos] = (int)(sd & 0x00FFFFFFu);
    }
}

// ---------------- weight pack: fp32 [K][Nout] -> bf16 in MFMA FRAGMENT ORDER ----------------
// Frag order: flat = (kb*8 + t)*512 + lane*8 + j, lane = q*16 + ln,
// holding W[k = kb*32 + q*8 + j][n = t*16 + ln]. A wave's B-frag load for
// (kb, t) is one contiguous 1KB burst. Fused: W1 (K=256) then [Wmu|Wlv] (K=128).

__global__ void pack_weights(const float* __restrict__ W1, const float* __restrict__ Wmu,
                             const float* __restrict__ Wlv,
                             short* __restrict__ w1f, short* __restrict__ wcatf) {
    int i = blockIdx.x * blockDim.x + threadIdx.x;
    if (i < 128 * 256) {
        int j  = i & 7;
        int ln = (i >> 3) & 15;
        int q  = (i >> 7) & 3;
        int t  = (i >> 9) & 7;
        int kb = i >> 12;
        int n = t * 16 + ln;
        int k = kb * 32 + q * 8 + j;
        w1f[i] = f2bf(W1[k * 128 + n]);
    } else {
        int i2 = i - 128 * 256;
        if (i2 < 128 * 128) {
            int j  = i2 & 7;
            int ln = (i2 >> 3) & 15;
            int q  = (i2 >> 7) & 3;
            int t  = (i2 >> 9) & 7;
            int kb = i2 >> 12;
            int n = t * 16 + ln;
            int k = kb * 32 + q * 8 + j;
            wcatf[i2] = f2bf((n < 64) ? Wmu[k * 64 + n] : Wlv[k * 64 + (n - 64)]);
        }
    }
}

// ---------------- MFMA GEMM: C[M,128](bf16) = A[M,K] @ W (bf16 frag-order) ----------------
// Block 128 thr = 2 waves; wave w: rows blk*64 + w*32 .. +31 (two 16-row A frags)
// -> 64 rows/block, ~782 blocks at N=50k: ~3 blocks/CU, even load balance.
// B frag (kb,t): contiguous 1KB burst from Bfrag. C/D: col=lane&15, row=q*4+reg (m89).
// Epilogue: scale row by dis[row], convert bf16.

template<int K, bool ABF16>
__launch_bounds__(128)
__global__ void gemm_mfma(const void* __restrict__ Ap, const short* __restrict__ Bfrag,
                          short* __restrict__ C, int M, const float* __restrict__ dis) {
    int w = threadIdx.x >> 6;
    int lane = threadIdx.x & 63;
    int ln = lane & 15;
    int q  = lane >> 4;
    int rowTile = blockIdx.x * 64 + w * 32;

    int r0 = rowTile + ln;
    int r1 = rowTile + 16 + ln;
    int r0c = (r0 < M) ? r0 : (M - 1);
    int r1c = (r1 < M) ? r1 : (M - 1);

    const float* a0F = (const float*)Ap + (size_t)r0c * K + q * 8;
    const float* a1F = (const float*)Ap + (size_t)r1c * K + q * 8;
    const short* a0B = (const short*)Ap + (size_t)r0c * K + q * 8;
    const short* a1B = (const short*)Ap + (size_t)r1c * K + q * 8;
    const short* bLane = Bfrag + lane * 8;

    floatx4 acc[2][8];
    #pragma unroll
    for (int f = 0; f < 2; f++)
        #pragma unroll
        for (int t = 0; t < 8; t++) acc[f][t] = (floatx4){0.f, 0.f, 0.f, 0.f};

    constexpr int NIT = K / 32;
    #pragma unroll
    for (int kb = 0; kb < NIT; kb++) {
        int kt = kb * 32;
        bf16x8 aF0, aF1;
        if (ABF16) {
            aF0 = *(const bf16x8*)(a0B + kt);
            aF1 = *(const bf16x8*)(a1B + kt);
        } else {
            float4 x0 = *(const float4*)(a0F + kt);
            float4 x1 = *(const float4*)(a0F + kt + 4);
            float4 y0 = *(const float4*)(a1F + kt);
            float4 y1 = *(const float4*)(a1F + kt + 4);
            aF0[0] = f2bf(x0.x); aF0[1] = f2bf(x0.y); aF0[2] = f2bf(x0.z); aF0[3] = f2bf(x0.w);
            aF0[4] = f2bf(x1.x); aF0[5] = f2bf(x1.y); aF0[6] = f2bf(x1.z); aF0[7] = f2bf(x1.w);
            aF1[0] = f2bf(y0.x); aF1[1] = f2bf(y0.y); aF1[2] = f2bf(y0.z); aF1[3] = f2bf(y0.w);
            aF1[4] = f2bf(y1.x); aF1[5] = f2bf(y1.y); aF1[6] = f2bf(y1.z); aF1[7] = f2bf(y1.w);
        }
        bf16x8 bF[8];
        #pragma unroll
        for (int t = 0; t < 8; t++)
            bF[t] = *(const bf16x8*)(bLane + (size_t)(kb * 8 + t) * 512);
        #pragma unroll
        for (int t = 0; t < 8; t++) {
            acc[0][t] = __builtin_amdgcn_mfma_f32_16x16x32_bf16(aF0, bF[t], acc[0][t], 0, 0, 0);
            acc[1][t] = __builtin_amdgcn_mfma_f32_16x16x32_bf16(aF1, bF[t], acc[1][t], 0, 0, 0);
        }
    }

    #pragma unroll
    for (int f = 0; f < 2; f++) {
        #pragma unroll
        for (int reg = 0; reg < 4; reg++) {
            int r = rowTile + f * 16 + q * 4 + reg;
            if (r < M) {
                float s = dis ? dis[r] : 1.f;
                #pragma unroll
                for (int t = 0; t < 8; t++)
                    C[(size_t)r * 128 + t * 16 + ln] = f2bf(s * acc[f][t][reg]);
            }
        }
    }
}

// ---------------- aggregation: one WAVE per node, bf16 rows, quarter-wave gathers ----------------
// zp holds pre-scaled bf16 rows z'[i] = dis[i] * (transform(x))[i]  (128 feats = 256B).
// out_node = dis[d] * ( sum_{s in N(d)} z'[s] + z'[d] ) + bias
// Quarter-wave qi handles slots e == start+qi (mod 4); unrolled x4 -> 16 independent
// row-gathers in flight per wave (MLP for L2/LLC latency).

#define AGG_BODY_BF16                                                         \
    int wave = threadIdx.x >> 6;                                              \
    int node = blockIdx.x * 4 + wave;                                         \
    if (node >= N) return;                                                    \
    int lane = threadIdx.x & 63;                                              \
    int qi = lane >> 4;                                                       \
    int fl = lane & 15;                                                       \
    int fo = fl * 8;                                                          \
    const short* zb = zp + fo;                                                \
    int start = row_ptr[node], end = row_end[node];                           \
    float acc[8];                                                             \
    _Pragma("unroll")                                                         \
    for (int j = 0; j < 8; j++) acc[j] = 0.f;                                 \
    int e = start + qi;                                                       \
    for (; e + 12 < end; e += 16) {                                           \
        int s0 = csr_src[e],     s1 = csr_src[e + 4];                         \
        int s2 = csr_src[e + 8], s3 = csr_src[e + 12];                        \
        bf16x8 z0 = *(const bf16x8*)(zb + (size_t)s0 * 128);                  \
        bf16x8 z1 = *(const bf16x8*)(zb + (size_t)s1 * 128);                  \
        bf16x8 z2 = *(const bf16x8*)(zb + (size_t)s2 * 128);                  \
        bf16x8 z3 = *(const bf16x8*)(zb + (size_t)s3 * 128);                  \
        _Pragma("unroll")                                                     \
        for (int j = 0; j < 8; j++)                                           \
            acc[j] += (bf2f(z0[j]) + bf2f(z1[j])) + (bf2f(z2[j]) + bf2f(z3[j])); \
    }                                                                         \
    for (; e < end; e += 4) {                                                 \
        int s0 = csr_src[e];                                                  \
        bf16x8 z0 = *(const bf16x8*)(zb + (size_t)s0 * 128);                  \
        _Pragma("unroll")                                                     \
        for (int j = 0; j < 8; j++) acc[j] += bf2f(z0[j]);                    \
    }                                                                         \
    if (qi == 0) {  /* self loop, added exactly once */                       \
        bf16x8 zs = *(const bf16x8*)(zb + (size_t)node * 128);                \
        _Pragma("unroll")                                                     \
        for (int j = 0; j < 8; j++) acc[j] += bf2f(zs[j]);                    \
    }                                                                         \
    _Pragma("unroll")                                                         \
    for (int j = 0; j < 8; j++) {                                             \
        acc[j] += __shfl_xor(acc[j], 16);                                     \
        acc[j] += __shfl_xor(acc[j], 32);                                     \
    }

__launch_bounds__(256)
__global__ void agg_layer1(const short* __restrict__ zp, const int* __restrict__ row_ptr,
                           const int* __restrict__ row_end, const int* __restrict__ csr_src,
                           const float* __restrict__ dis, const float* __restrict__ b1,
                           short* __restrict__ h, int N) {
    AGG_BODY_BF16
    if (qi == 0) {
        float d = dis[node];
        bf16x8 ov;
        #pragma unroll
        for (int j = 0; j < 8; j++) {
            float v = fmaf(d, acc[j], b1[fo + j]);
            v = (v > 0.f) ? v : NEG_SLOPE * v;
            ov[j] = f2bf(v);
        }
        *(bf16x8*)(h + (size_t)node * 128 + fo) = ov;
    }
}

__launch_bounds__(256)
__global__ void agg_layer2(const short* __restrict__ zp, const int* __restrict__ row_ptr,
                           const int* __restrict__ row_end, const int* __restrict__ csr_src,
                           const float* __restrict__ dis, const float* __restrict__ b_mu,
                           const float* __restrict__ b_lv, float* __restrict__ out, int N) {
    AGG_BODY_BF16
    if (qi == 0) {
        float d = dis[node];
        float r[8];
        if (fl < 8) {                        // mu: features fo..fo+7
            #pragma unroll
            for (int j = 0; j < 8; j++) r[j] = fmaf(d, acc[j], b_mu[fo + j]);
            float* p = out + (size_t)node * 64 + fo;
            *(float4*)p       = make_float4(r[0], r[1], r[2], r[3]);
            *(float4*)(p + 4) = make_float4(r[4], r[5], r[6], r[7]);
        } else {                             // logvar: features fo-64..fo-57
            #pragma unroll
            for (int j = 0; j < 8; j++) r[j] = fmaf(d, acc[j], b_lv[fo - 64 + j]);
            float* p = out + (size_t)N * 64 + (size_t)node * 64 + (fo - 64);
            *(float4*)p       = make_float4(r[0], r[1], r[2], r[3]);
            *(float4*)(p + 4) = make_float4(r[4], r[5], r[6], r[7]);
        }
    }
}

// ---------------- launcher ----------------

extern "C" void kernel_launch(void* const* d_in, const int* in_sizes, int n_in,
                              void* d_out, int out_size, void* d_ws, size_t ws_size,
                              hipStream_t stream) {
    const float* x   = (const float*)d_in[0];
    const int*   ei  = (const int*)d_in[1];    // [2,E] int32: src then dst
    const float* W1  = (const float*)d_in[2];
    const float* b1  = (const float*)d_in[3];
    const float* Wmu = (const float*)d_in[4];
    const float* bmu = (const float*)d_in[5];
    const float* Wlv = (const float*)d_in[6];
    const float* blv = (const float*)d_in[7];
    float* out = (float*)d_out;

    const int F_IN = 256;
    int N = in_sizes[0] / F_IN;   // 50000
    int E = in_sizes[1] / 2;      // 800000
    const int* e_src = ei;
    const int* e_dst = ei + E;

    char* ws = (char*)d_ws;
    size_t off = 0;
    auto carve = [&](size_t bytes) -> void* {
        void* p = ws + off;
        off += (bytes + 255) & ~(size_t)255;
        return p;
    };
    int*   row_end  = (int*)  carve((size_t)N * 4);
    int*   row_ptr  = (int*)  carve((size_t)N * 4);
    float* dis      = (float*)carve((size_t)N * 4);
    int*   csr_src  = (int*)  carve((size_t)E * 4);
    short* bufA     = (short*)carve((size_t)N * 128 * 2);  // bf16 Z1'/Z2'; aliased by `bucketed` pre-GEMM
    short* bufB     = (short*)carve((size_t)N * 128 * 2);  // bf16 h; aliased by `hist` pre-GEMM
    short* w1f      = (short*)carve(128 * 256 * 2);        // bf16 W1 frag-order
    short* wcatf    = (short*)carve(128 * 128 * 2);        // bf16 [Wmu|Wlv] frag-order
    int*   bstart   = (int*)  carve(4096);                 // bucket starts (K+1)

    // CSR-build scratch aliases the feature buffers (build fully precedes GEMMs)
    unsigned* bucketed = (unsigned*)bufA;   // E * 4B <= N*256B
    int*      hist     = (int*)bufB;        // K*B * 4B (~154 KB)

    int B = (E + EPB - 1) / EPB;            // edge blocks
    int K = (N + 255) >> NB_SHIFT;          // dst buckets

    // bucketed CSR build (degrees derived in-bucket; no node-level global scan)
    hipLaunchKernelGGL(bucket_hist, dim3(B), dim3(256), 0, stream, e_dst, E, B, K, hist);
    hipLaunchKernelGGL(bucket_starts, dim3(1), dim3(256), 0, stream, hist, B, K, E, bstart);
    hipLaunchKernelGGL(scan_hist_buckets, dim3(K), dim3(256), 0, stream, hist, bstart, B, K);
    hipLaunchKernelGGL(bucket_scatter, dim3(B), dim3(256), 0, stream, e_src, e_dst, E, B, K, hist, bucketed);
    hipLaunchKernelGGL(fill_csr_deg, dim3(K), dim3(256), 0, stream,
                       bucketed, bstart, row_ptr, row_end, dis, csr_src, N);
    // weight packs (frag order, fused)
    hipLaunchKernelGGL(pack_weights, dim3(192), dim3(256), 0, stream, W1, Wmu, Wlv, w1f, wcatf);
    // layer 1: Z1' = dis .* (x @ W1) ; h = leaky(dis .* Agg(Z1') + b1)
    hipLaunchKernelGGL((gemm_mfma<256, false>), dim3((N + 63) / 64), dim3(128), 0, stream,
                       (const void*)x, w1f, bufA, N, dis);
    hipLaunchKernelGGL(agg_layer1, dim3((N + 3) / 4), dim3(256), 0, stream,
                       bufA, row_ptr, row_end, csr_src, dis, b1, bufB, N);
    // layer 2 (mu & logvar share the aggregation): Z2' = dis .* (h @ [Wmu|Wlv])
    hipLaunchKernelGGL((gemm_mfma<128, true>), dim3((N + 63) / 64), dim3(128), 0, stream,
                       (const void*)bufB, wcatf, bufA, N, dis);
    hipLaunchKernelGGL(agg_layer2, dim3((N + 3) / 4), dim3(256), 0, stream,
                       bufA, row_ptr, row_end, csr_src, dis, bmu, blv, out, N);
}

// Round 10
// 247.902 us; speedup vs baseline: 1.0397x; 1.0397x over previous
//
#include <hip/hip_runtime.h>

#define NEG_SLOPE 0.01f
#define EPB 4096          // edges per block in bucket build
#define NB_SHIFT 8        // 256 dst-nodes per bucket

typedef __attribute__((ext_vector_type(8))) short bf16x8;
typedef __attribute__((ext_vector_type(4))) float floatx4;

__device__ __forceinline__ short f2bf(float f) {
    union { float f; unsigned u; } v; v.f = f;
    unsigned u = v.u;
    u += 0x7FFF + ((u >> 16) & 1);          // round-to-nearest-even
    return (short)(u >> 16);
}
__device__ __forceinline__ float bf2f(short s) {
    union { unsigned u; float f; } v;
    v.u = ((unsigned)(unsigned short)s) << 16;
    return v.f;
}

// ================= fused: bucket_hist + weight pack =================
// blocks [0,B): per-4096-edge dst-bucket histogram (hist[k*B+b], bucket k = dst>>8)
// blocks [B,B+192): pack W1 (K=256) then [Wmu|Wlv] (K=128) into MFMA frag order:
//   flat = (kb*8+t)*512 + lane*8 + j  holds  W[kb*32+q*8+j][t*16+ln], lane=q*16+ln.

__launch_bounds__(256)
__global__ void hist_pack(const int* __restrict__ dst, int E, int B, int K,
                          int* __restrict__ hist,
                          const float* __restrict__ W1, const float* __restrict__ Wmu,
                          const float* __restrict__ Wlv,
                          short* __restrict__ w1f, short* __restrict__ wcatf) {
    __shared__ int lh[1024];
    int bid = blockIdx.x;
    if (bid < B) {
        for (int i = threadIdx.x; i < K; i += 256) lh[i] = 0;
        __syncthreads();
        int lo = bid * EPB, hi = min(lo + EPB, E);
        for (int e = lo + threadIdx.x; e < hi; e += 256)
            atomicAdd(&lh[dst[e] >> NB_SHIFT], 1);
        __syncthreads();
        for (int i = threadIdx.x; i < K; i += 256)
            hist[i * B + bid] = lh[i];
    } else {
        int i = (bid - B) * 256 + threadIdx.x;
        if (i < 128 * 256) {
            int j  = i & 7;
            int ln = (i >> 3) & 15;
            int q  = (i >> 7) & 3;
            int t  = (i >> 9) & 7;
            int kb = i >> 12;
            int n = t * 16 + ln;
            int k = kb * 32 + q * 8 + j;
            w1f[i] = f2bf(W1[k * 128 + n]);
        } else {
            int i2 = i - 128 * 256;
            int j  = i2 & 7;
            int ln = (i2 >> 3) & 15;
            int q  = (i2 >> 7) & 3;
            int t  = (i2 >> 9) & 7;
            int kb = i2 >> 12;
            int n = t * 16 + ln;
            int k = kb * 32 + q * 8 + j;
            wcatf[i2] = f2bf((n < 64) ? Wmu[k * 64 + n] : Wlv[k * 64 + (n - 64)]);
        }
    }
}

// one block: bucket totals + exclusive scan -> bstart[0..K], bstart[K]=E
__global__ void bucket_starts(const int* __restrict__ hist, int B, int K, int E,
                              int* __restrict__ bstart) {
    __shared__ int tot[1024];
    __shared__ int waveTot[4];
    __shared__ int waveOff[5];
    int tid = threadIdx.x;                 // 256 threads
    for (int k = tid; k < K; k += 256) {
        const int* hp = hist + (size_t)k * B;
        int s = 0;
        for (int b = 0; b < B; b++) s += hp[b];
        tot[k] = s;
    }
    __syncthreads();
    int lane = tid & 63, wave = tid >> 6;
    int run = 0;
    for (int lo = 0; lo < K; lo += 256) {
        int i = lo + tid;
        int v = (i < K) ? tot[i] : 0;
        int s = v;
        #pragma unroll
        for (int o = 1; o < 64; o <<= 1) {
            int t = __shfl_up(s, o);
            if (lane >= o) s += t;
        }
        if (lane == 63) waveTot[wave] = s;
        __syncthreads();
        if (tid == 0) {
            int acc = 0;
            #pragma unroll
            for (int w = 0; w < 4; w++) { waveOff[w] = acc; acc += waveTot[w]; }
            waveOff[4] = acc;
        }
        __syncthreads();
        if (i < K) bstart[i] = run + s - v + waveOff[wave];
        run += waveOff[4];
        __syncthreads();
    }
    if (tid == 0) bstart[K] = E;
}

// per-bucket exclusive scan of hist[k*B .. k*B+B), seeded with bstart[k].
__global__ void scan_hist_buckets(int* __restrict__ hist, const int* __restrict__ bstart,
                                  int B, int K) {
    __shared__ int waveTot[4];
    __shared__ int waveOff[5];
    int k = blockIdx.x;
    int tid = threadIdx.x;
    int lane = tid & 63, wave = tid >> 6;
    int* hp = hist + (size_t)k * B;
    int run = bstart[k];
    for (int lo = 0; lo < B; lo += 256) {
        int i = lo + tid;
        int v = (i < B) ? hp[i] : 0;
        int s = v;
        #pragma unroll
        for (int o = 1; o < 64; o <<= 1) {
            int t = __shfl_up(s, o);
            if (lane >= o) s += t;
        }
        if (lane == 63) waveTot[wave] = s;
        __syncthreads();
        if (tid == 0) {
            int acc = 0;
            #pragma unroll
            for (int w = 0; w < 4; w++) { waveOff[w] = acc; acc += waveTot[w]; }
            waveOff[4] = acc;
        }
        __syncthreads();
        if (i < B) hp[i] = run + s - v + waveOff[wave];
        run += waveOff[4];
        __syncthreads();
    }
}

// ================= fused: bucket_scatter + GEMM1 (Z1 = x @ W1, UNSCALED) =================
// blocks [0,B): scatter edges into bucket-contiguous records src(u16) | local_dst<<24.
// blocks [B,..): MFMA GEMM1 tile (128 rows, 4 waves), no dis scaling (dis not yet known).

template<int K, bool ABF16, bool SCALE>
__device__ __forceinline__ void gemm_body(int blk, int tid, const void* __restrict__ Ap,
                                          const short* __restrict__ Bfrag,
                                          short* __restrict__ C, int M,
                                          const float* __restrict__ dis) {
    int w = tid >> 6;
    int lane = tid & 63;
    int ln = lane & 15;
    int q  = lane >> 4;
    int rowTile = blk * 128 + w * 32;

    int r0 = rowTile + ln;
    int r1 = rowTile + 16 + ln;
    int r0c = (r0 < M) ? r0 : (M - 1);
    int r1c = (r1 < M) ? r1 : (M - 1);

    const float* a0F = (const float*)Ap + (size_t)r0c * K + q * 8;
    const float* a1F = (const float*)Ap + (size_t)r1c * K + q * 8;
    const short* a0B = (const short*)Ap + (size_t)r0c * K + q * 8;
    const short* a1B = (const short*)Ap + (size_t)r1c * K + q * 8;
    const short* bLane = Bfrag + lane * 8;

    floatx4 acc[2][8];
    #pragma unroll
    for (int f = 0; f < 2; f++)
        #pragma unroll
        for (int t = 0; t < 8; t++) acc[f][t] = (floatx4){0.f, 0.f, 0.f, 0.f};

    constexpr int NIT = K / 32;
    #pragma unroll
    for (int kb = 0; kb < NIT; kb++) {
        int kt = kb * 32;
        bf16x8 aF0, aF1;
        if (ABF16) {
            aF0 = *(const bf16x8*)(a0B + kt);
            aF1 = *(const bf16x8*)(a1B + kt);
        } else {
            float4 x0 = *(const float4*)(a0F + kt);
            float4 x1 = *(const float4*)(a0F + kt + 4);
            float4 y0 = *(const float4*)(a1F + kt);
            float4 y1 = *(const float4*)(a1F + kt + 4);
            aF0[0] = f2bf(x0.x); aF0[1] = f2bf(x0.y); aF0[2] = f2bf(x0.z); aF0[3] = f2bf(x0.w);
            aF0[4] = f2bf(x1.x); aF0[5] = f2bf(x1.y); aF0[6] = f2bf(x1.z); aF0[7] = f2bf(x1.w);
            aF1[0] = f2bf(y0.x); aF1[1] = f2bf(y0.y); aF1[2] = f2bf(y0.z); aF1[3] = f2bf(y0.w);
            aF1[4] = f2bf(y1.x); aF1[5] = f2bf(y1.y); aF1[6] = f2bf(y1.z); aF1[7] = f2bf(y1.w);
        }
        bf16x8 bF[8];
        #pragma unroll
        for (int t = 0; t < 8; t++)
            bF[t] = *(const bf16x8*)(bLane + (size_t)(kb * 8 + t) * 512);
        #pragma unroll
        for (int t = 0; t < 8; t++) {
            acc[0][t] = __builtin_amdgcn_mfma_f32_16x16x32_bf16(aF0, bF[t], acc[0][t], 0, 0, 0);
            acc[1][t] = __builtin_amdgcn_mfma_f32_16x16x32_bf16(aF1, bF[t], acc[1][t], 0, 0, 0);
        }
    }

    #pragma unroll
    for (int f = 0; f < 2; f++) {
        #pragma unroll
        for (int reg = 0; reg < 4; reg++) {
            int r = rowTile + f * 16 + q * 4 + reg;
            if (r < M) {
                float s = SCALE ? dis[r] : 1.f;
                #pragma unroll
                for (int t = 0; t < 8; t++)
                    C[(size_t)r * 128 + t * 16 + ln] = f2bf(s * acc[f][t][reg]);
            }
        }
    }
}

__launch_bounds__(256)
__global__ void scatter_gemm1(const int* __restrict__ src, const int* __restrict__ dst,
                              int E, int B, int K, const int* __restrict__ scanned,
                              unsigned* __restrict__ bucketed,
                              const float* __restrict__ x, const short* __restrict__ w1f,
                              short* __restrict__ z1, int M) {
    __shared__ int lcur[1024];
    int bid = blockIdx.x;
    if (bid < B) {
        for (int i = threadIdx.x; i < K; i += 256) lcur[i] = scanned[i * B + bid];
        __syncthreads();
        int lo = bid * EPB, hi = min(lo + EPB, E);
        for (int e = lo + threadIdx.x; e < hi; e += 256) {
            int d = dst[e];
            unsigned rec = (unsigned)(src[e] & 0xFFFF) | ((unsigned)(d & 255) << 24);
            int pos = atomicAdd(&lcur[d >> NB_SHIFT], 1);
            bucketed[pos] = rec;
        }
    } else {
        gemm_body<256, false, false>(bid - B, threadIdx.x, (const void*)x, w1f, z1, M, nullptr);
    }
}

// one block per bucket: derive degrees, row_ptr/row_end/dis, then fill csr (ushort src).
__global__ void fill_csr_deg(const unsigned* __restrict__ bucketed,
                             const int* __restrict__ bstart,
                             int* __restrict__ row_ptr, int* __restrict__ row_end,
                             float* __restrict__ dis,
                             unsigned short* __restrict__ csr_src, int N) {
    __shared__ int cnt[256];
    __shared__ int rp[256];
    __shared__ int waveTot[4];
    __shared__ int waveOff[4];
    int k = blockIdx.x;
    int tid = threadIdx.x;
    int base = k << NB_SHIFT;
    cnt[tid] = 0;
    __syncthreads();
    int lo = bstart[k], hi = bstart[k + 1];
    for (int e = lo + tid; e < hi; e += 256)
        atomicAdd(&cnt[bucketed[e] >> 24], 1);
    __syncthreads();
    int v = cnt[tid];
    int lane = tid & 63, wave = tid >> 6;
    int s = v;
    #pragma unroll
    for (int o = 1; o < 64; o <<= 1) {
        int t = __shfl_up(s, o);
        if (lane >= o) s += t;
    }
    if (lane == 63) waveTot[wave] = s;
    __syncthreads();
    if (tid == 0) {
        int acc = 0;
        #pragma unroll
        for (int w = 0; w < 4; w++) { waveOff[w] = acc; acc += waveTot[w]; }
    }
    __syncthreads();
    int myrp = lo + s - v + waveOff[wave];
    rp[tid] = myrp;
    int node = base + tid;
    if (node < N) {
        row_ptr[node] = myrp;
        row_end[node] = myrp + v;
        dis[node] = rsqrtf(1.0f + (float)v);   // self-loop folded into degree
    }
    __syncthreads();
    for (int e = lo + tid; e < hi; e += 256) {
        unsigned sd = bucketed[e];
        int pos = atomicAdd(&rp[sd >> 24], 1);
        csr_src[pos] = (unsigned short)(sd & 0xFFFFu);
    }
}

// ================= aggregation (one wave/node, quarter-wave 16B row gathers) =================
// Layer 1: z1 is UNSCALED Z1 bf16; acc += dis[s] * row; out = leaky(dis[d]*acc + b1) -> bf16 h.

__launch_bounds__(256)
__global__ void agg_layer1(const short* __restrict__ z1, const int* __restrict__ row_ptr,
                           const int* __restrict__ row_end,
                           const unsigned short* __restrict__ csr_src,
                           const float* __restrict__ dis, const float* __restrict__ b1,
                           short* __restrict__ h, int N) {
    int wave = threadIdx.x >> 6;
    int node = blockIdx.x * 4 + wave;
    if (node >= N) return;
    int lane = threadIdx.x & 63;
    int qi = lane >> 4;
    int fl = lane & 15;
    int fo = fl * 8;
    const short* zb = z1 + fo;
    int start = row_ptr[node], end = row_end[node];
    float acc[8];
    #pragma unroll
    for (int j = 0; j < 8; j++) acc[j] = 0.f;
    int e = start + qi;
    for (; e + 4 < end; e += 8) {
        int s0 = csr_src[e], s1 = csr_src[e + 4];
        float d0 = dis[s0], d1 = dis[s1];
        bf16x8 z0 = *(const bf16x8*)(zb + (size_t)s0 * 128);
        bf16x8 zv1 = *(const bf16x8*)(zb + (size_t)s1 * 128);
        #pragma unroll
        for (int j = 0; j < 8; j++)
            acc[j] = fmaf(d0, bf2f(z0[j]), fmaf(d1, bf2f(zv1[j]), acc[j]));
    }
    for (; e < end; e += 4) {
        int s0 = csr_src[e];
        float d0 = dis[s0];
        bf16x8 z0 = *(const bf16x8*)(zb + (size_t)s0 * 128);
        #pragma unroll
        for (int j = 0; j < 8; j++) acc[j] = fmaf(d0, bf2f(z0[j]), acc[j]);
    }
    if (qi == 0) {  // self loop, once
        float dn = dis[node];
        bf16x8 zs = *(const bf16x8*)(zb + (size_t)node * 128);
        #pragma unroll
        for (int j = 0; j < 8; j++) acc[j] = fmaf(dn, bf2f(zs[j]), acc[j]);
    }
    #pragma unroll
    for (int j = 0; j < 8; j++) {
        acc[j] += __shfl_xor(acc[j], 16);
        acc[j] += __shfl_xor(acc[j], 32);
    }
    if (qi == 0) {
        float d = dis[node];
        bf16x8 ov;
        #pragma unroll
        for (int j = 0; j < 8; j++) {
            float v = fmaf(d, acc[j], b1[fo + j]);
            v = (v > 0.f) ? v : NEG_SLOPE * v;
            ov[j] = f2bf(v);
        }
        *(bf16x8*)(h + (size_t)node * 128 + fo) = ov;
    }
}

// Layer 2: zp is PRE-SCALED Z2' bf16 (dis applied in gemm2 epilogue); plain adds.

__launch_bounds__(256)
__global__ void agg_layer2(const short* __restrict__ zp, const int* __restrict__ row_ptr,
                           const int* __restrict__ row_end,
                           const unsigned short* __restrict__ csr_src,
                           const float* __restrict__ dis, const float* __restrict__ b_mu,
                           const float* __restrict__ b_lv, float* __restrict__ out, int N) {
    int wave = threadIdx.x >> 6;
    int node = blockIdx.x * 4 + wave;
    if (node >= N) return;
    int lane = threadIdx.x & 63;
    int qi = lane >> 4;
    int fl = lane & 15;
    int fo = fl * 8;
    const short* zb = zp + fo;
    int start = row_ptr[node], end = row_end[node];
    float acc[8];
    #pragma unroll
    for (int j = 0; j < 8; j++) acc[j] = 0.f;
    int e = start + qi;
    for (; e + 4 < end; e += 8) {
        int s0 = csr_src[e], s1 = csr_src[e + 4];
        bf16x8 z0 = *(const bf16x8*)(zb + (size_t)s0 * 128);
        bf16x8 z1 = *(const bf16x8*)(zb + (size_t)s1 * 128);
        #pragma unroll
        for (int j = 0; j < 8; j++) acc[j] += bf2f(z0[j]) + bf2f(z1[j]);
    }
    for (; e < end; e += 4) {
        int s0 = csr_src[e];
        bf16x8 z0 = *(const bf16x8*)(zb + (size_t)s0 * 128);
        #pragma unroll
        for (int j = 0; j < 8; j++) acc[j] += bf2f(z0[j]);
    }
    if (qi == 0) {
        bf16x8 zs = *(const bf16x8*)(zb + (size_t)node * 128);
        #pragma unroll
        for (int j = 0; j < 8; j++) acc[j] += bf2f(zs[j]);
    }
    #pragma unroll
    for (int j = 0; j < 8; j++) {
        acc[j] += __shfl_xor(acc[j], 16);
        acc[j] += __shfl_xor(acc[j], 32);
    }
    if (qi == 0) {
        float d = dis[node];
        float r[8];
        if (fl < 8) {                        // mu: features fo..fo+7
            #pragma unroll
            for (int j = 0; j < 8; j++) r[j] = fmaf(d, acc[j], b_mu[fo + j]);
            float* p = out + (size_t)node * 64 + fo;
            *(float4*)p       = make_float4(r[0], r[1], r[2], r[3]);
            *(float4*)(p + 4) = make_float4(r[4], r[5], r[6], r[7]);
        } else {                             // logvar: features fo-64..fo-57
            #pragma unroll
            for (int j = 0; j < 8; j++) r[j] = fmaf(d, acc[j], b_lv[fo - 64 + j]);
            float* p = out + (size_t)N * 64 + (size_t)node * 64 + (fo - 64);
            *(float4*)p       = make_float4(r[0], r[1], r[2], r[3]);
            *(float4*)(p + 4) = make_float4(r[4], r[5], r[6], r[7]);
        }
    }
}

// standalone GEMM2 (scaled epilogue)
__launch_bounds__(256)
__global__ void gemm2_kernel(const short* __restrict__ h, const short* __restrict__ wcatf,
                             short* __restrict__ z2, int M, const float* __restrict__ dis) {
    gemm_body<128, true, true>(blockIdx.x, threadIdx.x, (const void*)h, wcatf, z2, M, dis);
}

// ---------------- launcher ----------------

extern "C" void kernel_launch(void* const* d_in, const int* in_sizes, int n_in,
                              void* d_out, int out_size, void* d_ws, size_t ws_size,
                              hipStream_t stream) {
    const float* x   = (const float*)d_in[0];
    const int*   ei  = (const int*)d_in[1];    // [2,E] int32: src then dst
    const float* W1  = (const float*)d_in[2];
    const float* b1  = (const float*)d_in[3];
    const float* Wmu = (const float*)d_in[4];
    const float* bmu = (const float*)d_in[5];
    const float* Wlv = (const float*)d_in[6];
    const float* blv = (const float*)d_in[7];
    float* out = (float*)d_out;

    const int F_IN = 256;
    int N = in_sizes[0] / F_IN;   // 50000 (must be < 65536 for u16 csr)
    int E = in_sizes[1] / 2;      // 800000
    const int* e_src = ei;
    const int* e_dst = ei + E;

    char* ws = (char*)d_ws;
    size_t off = 0;
    auto carve = [&](size_t bytes) -> void* {
        void* p = ws + off;
        off += (bytes + 255) & ~(size_t)255;
        return p;
    };
    int*      row_end  = (int*)   carve((size_t)N * 4);
    int*      row_ptr  = (int*)   carve((size_t)N * 4);
    float*    dis      = (float*) carve((size_t)N * 4);
    unsigned short* csr_src = (unsigned short*)carve((size_t)E * 2);
    short*    bufA     = (short*) carve((size_t)N * 128 * 2);  // bf16 Z1 (unscaled), then Z2'
    short*    bufB     = (short*) carve((size_t)N * 128 * 2);  // bf16 h
    short*    w1f      = (short*) carve(128 * 256 * 2);        // bf16 W1 frag-order
    short*    wcatf    = (short*) carve(128 * 128 * 2);        // bf16 [Wmu|Wlv] frag-order
    int*      bstart   = (int*)   carve(4096);                 // bucket starts (K+1)
    unsigned* bucketed = (unsigned*)carve((size_t)E * 4);      // no aliasing (ws is large)
    int*      hist     = (int*)   carve((size_t)256 * 1024);   // K*B ints

    int B = (E + EPB - 1) / EPB;            // edge blocks (~196)
    int K = (N + 255) >> NB_SHIFT;          // dst buckets (~196)
    int Ggemm = (N + 127) / 128;            // gemm tiles (391)

    // K1: hist + weight pack (independent roles, one launch)
    hipLaunchKernelGGL(hist_pack, dim3(B + 192), dim3(256), 0, stream,
                       e_dst, E, B, K, hist, W1, Wmu, Wlv, w1f, wcatf);
    hipLaunchKernelGGL(bucket_starts, dim3(1), dim3(256), 0, stream, hist, B, K, E, bstart);
    hipLaunchKernelGGL(scan_hist_buckets, dim3(K), dim3(256), 0, stream, hist, bstart, B, K);
    // K4: edge scatter + GEMM1 (Z1 unscaled; independent of CSR)
    hipLaunchKernelGGL(scatter_gemm1, dim3(B + Ggemm), dim3(256), 0, stream,
                       e_src, e_dst, E, B, K, hist, bucketed, x, w1f, bufA, N);
    hipLaunchKernelGGL(fill_csr_deg, dim3(K), dim3(256), 0, stream,
                       bucketed, bstart, row_ptr, row_end, dis, csr_src, N);
    // h = leaky(dis_d * sum(dis_s * Z1[s]) + b1)
    hipLaunchKernelGGL(agg_layer1, dim3((N + 3) / 4), dim3(256), 0, stream,
                       bufA, row_ptr, row_end, csr_src, dis, b1, bufB, N);
    // Z2' = dis .* (h @ [Wmu|Wlv])
    hipLaunchKernelGGL(gemm2_kernel, dim3(Ggemm), dim3(256), 0, stream,
                       bufB, wcatf, bufA, N, dis);
    hipLaunchKernelGGL(agg_layer2, dim3((N + 3) / 4), dim3(256), 0, stream,
                       bufA, row_ptr, row_end, csr_src, dis, bmu, blv, out, N);
}